// Round 6
// baseline (69.773 us; speedup 1.0000x reference)
//
#include <hip/hip_runtime.h>

#define FEAT_D 4096
#define MARGIN_F 0.5f
#define EPS_F 1e-6f
#define ROWS_PER_BLK 8
#define NSLOT 64            // spread accumulator slots, 128 B apart
#define SLOT_STRIDE 32      // floats (128 B)

__global__ __launch_bounds__(256) void triplet_loss_kernel(
    const float* __restrict__ features,
    const float* __restrict__ label,
    const int* __restrict__ idx1,
    const int* __restrict__ idx2,
    float* __restrict__ accum)
{
    const int tid = threadIdx.x;
    const int row0 = blockIdx.x * ROWS_PER_BLK;

    __shared__ float sh1[ROWS_PER_BLK][4], sh2[ROWS_PER_BLK][4];
    __shared__ float shl[ROWS_PER_BLK];

    float4 bufA[12], bufB[12];

#define ISSUE(BUF, R)                                                          \
    {                                                                          \
        const int rr_ = (R);                                                   \
        const int j1_ = idx1[rr_], j2_ = idx2[rr_];                            \
        const float4* pa_ = reinterpret_cast<const float4*>(features + (size_t)rr_ * FEAT_D) + tid; \
        const float4* p1_ = reinterpret_cast<const float4*>(features + (size_t)j1_ * FEAT_D) + tid; \
        const float4* p2_ = reinterpret_cast<const float4*>(features + (size_t)j2_ * FEAT_D) + tid; \
        _Pragma("unroll")                                                      \
        for (int k = 0; k < 4; ++k) BUF[k]     = pa_[k * 256];                 \
        _Pragma("unroll")                                                      \
        for (int k = 0; k < 4; ++k) BUF[4 + k] = p1_[k * 256];                 \
        _Pragma("unroll")                                                      \
        for (int k = 0; k < 4; ++k) BUF[8 + k] = p2_[k * 256];                 \
    }                                                                          \
    __builtin_amdgcn_sched_barrier(0);

#define COMPUTE(BUF, SLOT)                                                     \
    {                                                                          \
        float s1_ = 0.f, s2_ = 0.f;                                            \
        _Pragma("unroll")                                                      \
        for (int k = 0; k < 4; ++k) {                                          \
            float d_;                                                          \
            d_ = BUF[k].x - BUF[4+k].x + EPS_F; s1_ += d_ * d_;                \
            d_ = BUF[k].y - BUF[4+k].y + EPS_F; s1_ += d_ * d_;                \
            d_ = BUF[k].z - BUF[4+k].z + EPS_F; s1_ += d_ * d_;                \
            d_ = BUF[k].w - BUF[4+k].w + EPS_F; s1_ += d_ * d_;                \
            d_ = BUF[k].x - BUF[8+k].x + EPS_F; s2_ += d_ * d_;                \
            d_ = BUF[k].y - BUF[8+k].y + EPS_F; s2_ += d_ * d_;                \
            d_ = BUF[k].z - BUF[8+k].z + EPS_F; s2_ += d_ * d_;                \
            d_ = BUF[k].w - BUF[8+k].w + EPS_F; s2_ += d_ * d_;                \
        }                                                                      \
        _Pragma("unroll")                                                      \
        for (int off = 32; off > 0; off >>= 1) {                               \
            s1_ += __shfl_down(s1_, off, 64);                                  \
            s2_ += __shfl_down(s2_, off, 64);                                  \
        }                                                                      \
        if ((tid & 63) == 0) { sh1[SLOT][tid >> 6] = s1_; sh2[SLOT][tid >> 6] = s2_; } \
    }

    ISSUE(bufA, row0)
    ISSUE(bufB, row0 + 1)
    COMPUTE(bufA, 0)
    ISSUE(bufA, row0 + 2)
    COMPUTE(bufB, 1)
    ISSUE(bufB, row0 + 3)
    COMPUTE(bufA, 2)
    ISSUE(bufA, row0 + 4)
    COMPUTE(bufB, 3)
    ISSUE(bufB, row0 + 5)
    COMPUTE(bufA, 4)
    ISSUE(bufA, row0 + 6)
    COMPUTE(bufB, 5)
    ISSUE(bufB, row0 + 7)
    COMPUTE(bufA, 6)
    COMPUTE(bufB, 7)

    __syncthreads();

    if (tid < ROWS_PER_BLK) {
        const int r = row0 + tid;
        const float S1 = sh1[tid][0] + sh1[tid][1] + sh1[tid][2] + sh1[tid][3];
        const float S2 = sh2[tid][0] + sh2[tid][1] + sh2[tid][2] + sh2[tid][3];
        const float lab = label[r];
        const float d1 = fabsf(lab - label[idx1[r]]);
        const float d2 = fabsf(lab - label[idx2[r]]);
        const bool swap = (d1 >= d2);
        const float sn = swap ? S2 : S1;
        const float sf = swap ? S1 : S2;
        shl[tid] = fmaxf(sqrtf(sn) - sqrtf(sf) + MARGIN_F, 0.f);
    }
    __syncthreads();

    if (tid == 0) {
        float t = 0.f;
#pragma unroll
        for (int r = 0; r < ROWS_PER_BLK; ++r) t += shl[r];
        // one atomic per block, spread over 64 cache lines (16 adds/line)
        atomicAdd(&accum[(blockIdx.x & (NSLOT - 1)) * SLOT_STRIDE], t);
    }
#undef ISSUE
#undef COMPUTE
}

__global__ __launch_bounds__(64) void final_reduce_kernel(
    const float* __restrict__ accum, float* __restrict__ out)
{
    const int lane = threadIdx.x;
    float s = accum[lane * SLOT_STRIDE];
#pragma unroll
    for (int off = 32; off > 0; off >>= 1)
        s += __shfl_down(s, off, 64);
    if (lane == 0) out[0] = s;
}

extern "C" void kernel_launch(void* const* d_in, const int* in_sizes, int n_in,
                              void* d_out, int out_size, void* d_ws, size_t ws_size,
                              hipStream_t stream) {
    const float* features = (const float*)d_in[0];
    const float* label    = (const float*)d_in[1];
    const int*   idx1     = (const int*)d_in[2];
    const int*   idx2     = (const int*)d_in[3];
    float* out   = (float*)d_out;
    float* accum = (float*)d_ws;   // NSLOT * SLOT_STRIDE floats = 8 KB

    const int B = in_sizes[1];  // label has B elements ([B,1])

    hipMemsetAsync(accum, 0, NSLOT * SLOT_STRIDE * sizeof(float), stream);
    triplet_loss_kernel<<<B / ROWS_PER_BLK, 256, 0, stream>>>(features, label, idx1, idx2, accum);
    final_reduce_kernel<<<1, 64, 0, stream>>>(accum, out);
}

// Round 7
// 64.516 us; speedup vs baseline: 1.0815x; 1.0815x over previous
//
#include <hip/hip_runtime.h>

#define FEAT_D 4096
#define MARGIN_F 0.5f
#define EPS_F 1e-6f
#define ROWS_PER_BLK 4

// Best-measured structure (round 4): 2048 blocks x 256 threads, 4 rows/block,
// 2-deep register double-buffer across rows, one partial float per block.

__global__ __launch_bounds__(256) void triplet_loss_kernel(
    const float* __restrict__ features,
    const float* __restrict__ label,
    const int* __restrict__ idx1,
    const int* __restrict__ idx2,
    float* __restrict__ partials)
{
    const int tid = threadIdx.x;
    const int row0 = blockIdx.x * ROWS_PER_BLK;

    __shared__ float sh1[ROWS_PER_BLK][4], sh2[ROWS_PER_BLK][4];
    __shared__ float shl[ROWS_PER_BLK];

    float4 bufA[12], bufB[12];

#define ISSUE(BUF, R)                                                          \
    {                                                                          \
        const int rr_ = (R);                                                   \
        const int j1_ = idx1[rr_], j2_ = idx2[rr_];                            \
        const float4* pa_ = reinterpret_cast<const float4*>(features + (size_t)rr_ * FEAT_D) + tid; \
        const float4* p1_ = reinterpret_cast<const float4*>(features + (size_t)j1_ * FEAT_D) + tid; \
        const float4* p2_ = reinterpret_cast<const float4*>(features + (size_t)j2_ * FEAT_D) + tid; \
        _Pragma("unroll")                                                      \
        for (int k = 0; k < 4; ++k) BUF[k]     = pa_[k * 256];                 \
        _Pragma("unroll")                                                      \
        for (int k = 0; k < 4; ++k) BUF[4 + k] = p1_[k * 256];                 \
        _Pragma("unroll")                                                      \
        for (int k = 0; k < 4; ++k) BUF[8 + k] = p2_[k * 256];                 \
    }                                                                          \
    __builtin_amdgcn_sched_barrier(0);

#define COMPUTE(BUF, SLOT)                                                     \
    {                                                                          \
        float s1_ = 0.f, s2_ = 0.f;                                            \
        _Pragma("unroll")                                                      \
        for (int k = 0; k < 4; ++k) {                                          \
            float d_;                                                          \
            d_ = BUF[k].x - BUF[4+k].x + EPS_F; s1_ += d_ * d_;                \
            d_ = BUF[k].y - BUF[4+k].y + EPS_F; s1_ += d_ * d_;                \
            d_ = BUF[k].z - BUF[4+k].z + EPS_F; s1_ += d_ * d_;                \
            d_ = BUF[k].w - BUF[4+k].w + EPS_F; s1_ += d_ * d_;                \
            d_ = BUF[k].x - BUF[8+k].x + EPS_F; s2_ += d_ * d_;                \
            d_ = BUF[k].y - BUF[8+k].y + EPS_F; s2_ += d_ * d_;                \
            d_ = BUF[k].z - BUF[8+k].z + EPS_F; s2_ += d_ * d_;                \
            d_ = BUF[k].w - BUF[8+k].w + EPS_F; s2_ += d_ * d_;                \
        }                                                                      \
        _Pragma("unroll")                                                      \
        for (int off = 32; off > 0; off >>= 1) {                               \
            s1_ += __shfl_down(s1_, off, 64);                                  \
            s2_ += __shfl_down(s2_, off, 64);                                  \
        }                                                                      \
        if ((tid & 63) == 0) { sh1[SLOT][tid >> 6] = s1_; sh2[SLOT][tid >> 6] = s2_; } \
    }

    ISSUE(bufA, row0)
    ISSUE(bufB, row0 + 1)
    COMPUTE(bufA, 0)
    ISSUE(bufA, row0 + 2)
    COMPUTE(bufB, 1)
    ISSUE(bufB, row0 + 3)
    COMPUTE(bufA, 2)
    COMPUTE(bufB, 3)

    __syncthreads();

    if (tid < ROWS_PER_BLK) {
        const int r = row0 + tid;
        const float S1 = sh1[tid][0] + sh1[tid][1] + sh1[tid][2] + sh1[tid][3];
        const float S2 = sh2[tid][0] + sh2[tid][1] + sh2[tid][2] + sh2[tid][3];
        const float lab = label[r];
        const float d1 = fabsf(lab - label[idx1[r]]);
        const float d2 = fabsf(lab - label[idx2[r]]);
        const bool swap = (d1 >= d2);
        const float sn = swap ? S2 : S1;
        const float sf = swap ? S1 : S2;
        shl[tid] = fmaxf(sqrtf(sn) - sqrtf(sf) + MARGIN_F, 0.f);
    }
    __syncthreads();

    if (tid == 0) {
        float t = (shl[0] + shl[1]) + (shl[2] + shl[3]);
        partials[blockIdx.x] = t;   // one coalesced-line store per block
    }
#undef ISSUE
#undef COMPUTE
}

__global__ __launch_bounds__(1024) void reduce_kernel(
    const float* __restrict__ partials, float* __restrict__ out, int n)
{
    const int tid = threadIdx.x;
    float s = 0.f;
    for (int i = tid; i < n; i += 1024)
        s += partials[i];
#pragma unroll
    for (int off = 32; off > 0; off >>= 1)
        s += __shfl_down(s, off, 64);

    __shared__ float sh[16];
    const int wave = tid >> 6;
    const int lane = tid & 63;
    if (lane == 0) sh[wave] = s;
    __syncthreads();
    if (tid == 0) {
        float t = 0.f;
#pragma unroll
        for (int w = 0; w < 16; ++w) t += sh[w];
        out[0] = t;
    }
}

extern "C" void kernel_launch(void* const* d_in, const int* in_sizes, int n_in,
                              void* d_out, int out_size, void* d_ws, size_t ws_size,
                              hipStream_t stream) {
    const float* features = (const float*)d_in[0];
    const float* label    = (const float*)d_in[1];
    const int*   idx1     = (const int*)d_in[2];
    const int*   idx2     = (const int*)d_in[3];
    float* out      = (float*)d_out;
    float* partials = (float*)d_ws;   // B/ROWS_PER_BLK floats = 8 KB scratch

    const int B = in_sizes[1];  // label has B elements ([B,1])
    const int nblk = B / ROWS_PER_BLK;

    triplet_loss_kernel<<<nblk, 256, 0, stream>>>(features, label, idx1, idx2, partials);
    reduce_kernel<<<1, 1024, 0, stream>>>(partials, out, nblk);
}